// Round 2
// 145.169 us; speedup vs baseline: 1.1190x; 1.1190x over previous
//
#include <hip/hip_runtime.h>
#include <hip/hip_bf16.h>

#define NN 100000
#define NE 1600000
#define NF 128
#define UU 64

typedef __attribute__((ext_vector_type(8))) short short8;
typedef __attribute__((ext_vector_type(4))) float f32x4;

// ---------------- workspace layout (bytes) ----------------
static const size_t OFF_FLAG = 0;                               // 256
static const size_t OFF_H2   = 256;                             // NN*64*2 (bf16)
static const size_t OFF_AD   = OFF_H2  + (size_t)NN * UU * 2;   // NN*4
static const size_t OFF_AS   = OFF_AD  + (size_t)NN * 4;        // NN*4
static const size_t OFF_ROW  = OFF_AS  + (size_t)NN * 4;        // (NN+1)*4
static const size_t OFF_WP   = OFF_ROW + (size_t)(NN + 1) * 4;  // 8192 bf16 (16KB)

__device__ __forceinline__ unsigned short bfr(float v) {
    unsigned u = __float_as_uint(v);
    return (unsigned short)((u + 0x7FFFu + ((u >> 16) & 1u)) >> 16);
}

// prep: edge-format flag + W packed into MFMA B-fragment-linear bf16 layout.
__global__ __launch_bounds__(256) void prep(const int* __restrict__ ew,
                                            const float* __restrict__ W,
                                            int* __restrict__ flag,
                                            unsigned short* __restrict__ Wp) {
    if (blockIdx.x == 0) {
        if (threadIdx.x == 0) {
            int a = ew[2 * 400000 + 1] | ew[2 * 800000 + 1] |
                    ew[2 * 1200000 + 1] | ew[2 * 1599999 + 1];
            *flag = (a == 0) ? 1 : 0;   // 1 => int64
        }
        return;
    }
    int i = (blockIdx.x - 1) * 256 + threadIdx.x;   // 32*256 = 8192
    int j   = i & 7;
    int l15 = (i >> 3) & 15;
    int quad = (i >> 7) & 3;
    int kb  = (i >> 9) & 3;
    int nt  = i >> 11;
    Wp[i] = bfr(W[(size_t)(kb * 32 + quad * 8 + j) * UU + nt * 16 + l15]);
}

#define GEMM_BLOCKS   1563  // ceil(NN/64)
#define ROWS_BLOCKS   391   // ceil((NN+1)/256)

__global__ __launch_bounds__(256) void mega(const float* __restrict__ X,
                                            const void* __restrict__ edges,
                                            const int* __restrict__ flag,
                                            const unsigned short* __restrict__ Wp,
                                            const float* __restrict__ ka,
                                            unsigned short* __restrict__ h2,
                                            float* __restrict__ a_dst,
                                            float* __restrict__ a_src,
                                            int* __restrict__ rows) {
    int bid = blockIdx.x;
    int tid = threadIdx.x;

    if (bid < GEMM_BLOCKS) {
        // ---- MFMA GEMM: h = X @ W. Block = 64 nodes (4 waves x 16). ----
        int wv = tid >> 6, lane = tid & 63;
        int quad = lane >> 4, l15 = lane & 15;
        int nb = bid * 64 + wv * 16;
        int row = nb + l15; if (row >= NN) row = NN - 1;   // clamped: stores guarded
        const float* xr = X + (size_t)row * NF + quad * 8;

        short8 afrag[4];
#pragma unroll
        for (int kb = 0; kb < 4; kb++) {
            float4 p0 = *(const float4*)(xr + kb * 32);
            float4 p1 = *(const float4*)(xr + kb * 32 + 4);
            short8 a;
            a[0] = (short)bfr(p0.x); a[1] = (short)bfr(p0.y);
            a[2] = (short)bfr(p0.z); a[3] = (short)bfr(p0.w);
            a[4] = (short)bfr(p1.x); a[5] = (short)bfr(p1.y);
            a[6] = (short)bfr(p1.z); a[7] = (short)bfr(p1.w);
            afrag[kb] = a;
        }

        f32x4 acc[4] = {f32x4{0,0,0,0}, f32x4{0,0,0,0}, f32x4{0,0,0,0}, f32x4{0,0,0,0}};
        const short8* wpf = (const short8*)Wp;
#pragma unroll
        for (int nt = 0; nt < 4; nt++) {
#pragma unroll
            for (int kb = 0; kb < 4; kb++) {
                short8 b = wpf[((nt * 4 + kb) * 4 + quad) * 16 + l15];
                acc[nt] = __builtin_amdgcn_mfma_f32_16x16x32_bf16(afrag[kb], b, acc[nt], 0, 0, 0);
            }
        }

        float kad[4], kas[4];
#pragma unroll
        for (int nt = 0; nt < 4; nt++) {
            kad[nt] = ka[nt * 16 + l15];
            kas[nt] = ka[64 + nt * 16 + l15];
        }
#pragma unroll
        for (int r = 0; r < 4; r++) {
            int m = nb + quad * 4 + r;
            if (m < NN) {
#pragma unroll
                for (int nt = 0; nt < 4; nt++)
                    h2[(size_t)m * UU + nt * 16 + l15] = bfr(acc[nt][r]);
            }
            float pd = acc[0][r] * kad[0] + acc[1][r] * kad[1] + acc[2][r] * kad[2] + acc[3][r] * kad[3];
            float ps = acc[0][r] * kas[0] + acc[1][r] * kas[1] + acc[2][r] * kas[2] + acc[3][r] * kas[3];
            pd += __shfl_xor(pd, 1); pd += __shfl_xor(pd, 2);
            pd += __shfl_xor(pd, 4); pd += __shfl_xor(pd, 8);
            ps += __shfl_xor(ps, 1); ps += __shfl_xor(ps, 2);
            ps += __shfl_xor(ps, 4); ps += __shfl_xor(ps, 8);
            if (l15 == 0 && m < NN) { a_dst[m] = pd; a_src[m] = ps; }
        }
        return;
    }
    bid -= GEMM_BLOCKS;

    // ---- CSR row offsets by binary search on ORIGINAL edges ----
    {
        int n = bid * 256 + tid;
        if (n > NN) return;
        if (n == NN) { rows[NN] = NE; return; }
        int fl = *flag;
        const int* ew = (const int*)edges;
        int lo = 0, hi = NE;
        while (lo < hi) {
            int mid = (lo + hi) >> 1;
            int d = fl ? ew[4 * (size_t)mid] : ew[2 * (size_t)mid];
            if (d < n) lo = mid + 1; else hi = mid;
        }
        rows[n] = lo;
    }
}

__device__ __forceinline__ float edge_score(float ad, float as) {
    float sc = ad + as;
    sc = sc > 0.f ? sc : 0.2f * sc;
    sc = fminf(fmaxf(sc, -2.f), 2.f);
    return __expf(sc);
}

// One 16-lane group per node (4 nodes/wave, 16 nodes/block).
// Fused: weight w_e = exp(clip(lrelu(a_dst[n] + a_src[src_e]))) computed inline
// (a_dst[n] is group-uniform; a_src is a 400KB L2-resident table).
// Gather: 16 lanes x uint2 = full 128B h2 row per edge, 4-deep batched.
// Lanes already own their 4 output columns -> no cross-group reduce, full-lane store.
__global__ __launch_bounds__(256) void aggregate(const void* __restrict__ edges,
                                                 const int* __restrict__ flag,
                                                 const int* __restrict__ rows,
                                                 const float* __restrict__ a_dst,
                                                 const float* __restrict__ a_src,
                                                 const unsigned short* __restrict__ h2,
                                                 float* __restrict__ out) {
    int tid = threadIdx.x;
    int lane = tid & 63;
    int g = lane >> 4, gl = lane & 15;
    int n = blockIdx.x * 16 + (tid >> 6) * 4 + g;
    if (n >= NN) return;
    int s = rows[n], e = rows[n + 1];
    int cnt = e - s;
    float ad = a_dst[n];
    int fl = *flag;
    const int* ew = (const int*)edges;
    // src word: int64 fmt -> word 4*i+2 == (ew+2)[4*i]; int32 fmt -> word 2*i+1 == (ew+1)[2*i]
    const int* sp = ew + (fl ? 2 : 1);
    int lsh = fl ? 2 : 1;
    const unsigned short* h2g = h2 + gl * 4;
    int gbase = g * 16;
    float4 acc = make_float4(0.f, 0.f, 0.f, 0.f);
    float inv;

#define BATCH(MS, MW, BOFF)                                                  \
    {                                                                        \
        uint2 rr[4]; float sw[4]; int sjv[4];                                \
        _Pragma("unroll")                                                    \
        for (int t = 0; t < 4; t++) {                                        \
            sjv[t] = __shfl(MS, gbase + (BOFF) + t);                         \
            sw[t]  = __shfl(MW, gbase + (BOFF) + t);                         \
        }                                                                    \
        _Pragma("unroll")                                                    \
        for (int t = 0; t < 4; t++)                                          \
            rr[t] = *(const uint2*)(h2g + (size_t)sjv[t] * UU);              \
        _Pragma("unroll")                                                    \
        for (int t = 0; t < 4; t++) {                                        \
            acc.x += sw[t] * __uint_as_float(rr[t].x << 16);                 \
            acc.y += sw[t] * __uint_as_float(rr[t].x & 0xFFFF0000u);         \
            acc.z += sw[t] * __uint_as_float(rr[t].y << 16);                 \
            acc.w += sw[t] * __uint_as_float(rr[t].y & 0xFFFF0000u);         \
        }                                                                    \
    }

    if (cnt <= 64) {
        // all edges + weights in registers; 4 independent load chains per chunk set
        int msrc[4]; float mw[4];
#pragma unroll
        for (int k = 0; k < 4; k++) {
            int c = k * 16 + gl;
            int sj = 0; float w = 0.f;
            if (c < cnt) {
                sj = sp[(size_t)(s + c) << lsh];
                w = edge_score(ad, a_src[sj]);
            }
            msrc[k] = sj; mw[k] = w;
        }
        float t0 = (mw[0] + mw[1]) + (mw[2] + mw[3]);
        t0 += __shfl_xor(t0, 1); t0 += __shfl_xor(t0, 2);
        t0 += __shfl_xor(t0, 4); t0 += __shfl_xor(t0, 8);
        inv = (cnt > 0) ? 1.f / t0 : 0.f;
#pragma unroll
        for (int k = 0; k < 4; k++) {
#pragma unroll
            for (int b = 0; b < 4; b++) {
                if (k * 16 + b * 4 < cnt) BATCH(msrc[k], mw[k], b * 4);
            }
        }
    } else {
        // rare fallback (Poisson(16) degree): two streaming passes with recompute
        float t0 = 0.f;
        for (int c = gl; c < cnt; c += 16) {
            int sj = sp[(size_t)(s + c) << lsh];
            t0 += edge_score(ad, a_src[sj]);
        }
        t0 += __shfl_xor(t0, 1); t0 += __shfl_xor(t0, 2);
        t0 += __shfl_xor(t0, 4); t0 += __shfl_xor(t0, 8);
        inv = 1.f / t0;
        for (int c0 = 0; c0 < cnt; c0 += 16) {
            int c = c0 + gl;
            int sj = 0; float w = 0.f;
            if (c < cnt) {
                sj = sp[(size_t)(s + c) << lsh];
                w = edge_score(ad, a_src[sj]);
            }
#pragma unroll
            for (int b = 0; b < 4; b++) {
                if (c0 + b * 4 < cnt) BATCH(sj, w, b * 4);
            }
        }
    }
#undef BATCH

    float4 o;
    o.x = acc.x * inv; o.y = acc.y * inv;
    o.z = acc.z * inv; o.w = acc.w * inv;
    *(float4*)(out + (size_t)n * UU + gl * 4) = o;
}

extern "C" void kernel_launch(void* const* d_in, const int* in_sizes, int n_in,
                              void* d_out, int out_size, void* d_ws, size_t ws_size,
                              hipStream_t stream) {
    const float* X  = (const float*)d_in[0];
    const void*  Ed = d_in[1];
    const float* W  = (const float*)d_in[2];
    const float* KA = (const float*)d_in[3];
    float* out = (float*)d_out;

    char* ws = (char*)d_ws;
    int*            flag  = (int*)(ws + OFF_FLAG);
    unsigned short* h2    = (unsigned short*)(ws + OFF_H2);
    float*          a_dst = (float*)(ws + OFF_AD);
    float*          a_src = (float*)(ws + OFF_AS);
    int*            rows  = (int*)(ws + OFF_ROW);
    unsigned short* Wp    = (unsigned short*)(ws + OFF_WP);

    prep<<<33, 256, 0, stream>>>((const int*)Ed, W, flag, Wp);
    mega<<<GEMM_BLOCKS + ROWS_BLOCKS, 256, 0, stream>>>(
        X, Ed, flag, Wp, KA, h2, a_dst, a_src, rows);
    aggregate<<<NN / 16, 256, 0, stream>>>(Ed, flag, rows, a_dst, a_src, h2, out);
}